// Round 1
// 182.867 us; speedup vs baseline: 1.0828x; 1.0828x over previous
//
#include <hip/hip_runtime.h>
#include <hip/hip_bf16.h>

#define SEQ   2048
#define EMB   1024
#define NHEAD 16
#define DHEAD 64
#define BATCH 2
#define MTOT  (BATCH*SEQ)   // 4096
#define QT    128           // queries per attention block
#define KT    64            // keys per tile

typedef __attribute__((ext_vector_type(8))) short s8v;   // 8 bf16 (4 VGPRs)
typedef __attribute__((ext_vector_type(4))) short s4v;   // 4 bf16 (8 B)
typedef __attribute__((ext_vector_type(4))) float f4v;   // mfma accum

__device__ __forceinline__ short f2b(float f) {
    union { float fl; unsigned u; } v; v.fl = f;
    unsigned u = v.u;
    u = (u + 0x7fffu + ((u >> 16) & 1u)) >> 16;   // round-to-nearest-even
    return (short)u;
}
// packed fp32x2 -> bf16x2 (v_cvt_pk_bf16_f32); rounded values also feed the
// softmax denominator (consistency => rounding-mode-agnostic).
__device__ __forceinline__ unsigned pk2(float a, float b) {
    union { __hip_bfloat162 h; unsigned u; } c;
    c.h = __float22bfloat162_rn(float2{a, b});
    return c.u;
}

#if __has_builtin(__builtin_amdgcn_exp2f)
__device__ __forceinline__ float exp2_fast(float x) { return __builtin_amdgcn_exp2f(x); }
#else
__device__ __forceinline__ float exp2_fast(float x) { return exp2f(x); }
#endif

// Raw workgroup barrier: LDS-visibility only (lgkmcnt drain), does NOT drain
// vmcnt — outstanding global prefetch loads stay in flight across it.
__device__ __forceinline__ void bar_lds() {
    asm volatile("s_waitcnt lgkmcnt(0)\n\ts_barrier" ::: "memory");
}

// async global->LDS DMA, 16 B/lane; LDS dest = wave-uniform base + lane*16.
__device__ __forceinline__ void gl_lds16(const short* g, short* l) {
    __builtin_amdgcn_global_load_lds(
        (const __attribute__((address_space(1))) void*)g,
        (__attribute__((address_space(3))) void*)l, 16, 0, 0);
}

// ---- fp32 -> bf16 convert + chunk swizzle ----
// Output rows are 1024 bf16 = 16 aligned 128B groups of 8 16B-chunks.
// Chunk c of row r is stored at slot (c&~7) | ((c&7) ^ (r&7)) so that
// global_load_lds' contiguous DMA lands a bank-uniform LDS image.
__global__ __launch_bounds__(256)
void cvt_swz(const float* __restrict__ s0, const float* __restrict__ s1,
             const float* __restrict__ s2, const float* __restrict__ s3,
             const float* __restrict__ s4,
             short* __restrict__ d0, short* __restrict__ d1,
             short* __restrict__ d2, short* __restrict__ d3,
             short* __restrict__ d4)
{
    const int seg = blockIdx.y;
    const float* s = seg == 0 ? s0 : seg == 1 ? s1 : seg == 2 ? s2 : seg == 3 ? s3 : s4;
    short*       d = seg == 0 ? d0 : seg == 1 ? d1 : seg == 2 ? d2 : seg == 3 ? d3 : d4;
    const int nchunk = (seg == 0 ? MTOT * EMB : EMB * EMB) / 8;   // 16B chunks
    const int stride = gridDim.x * 256;
    for (int i = blockIdx.x * 256 + threadIdx.x; i < nchunk; i += stride) {
        const int row = i >> 7;         // 128 chunks per 1024-col row
        const int c   = i & 127;
        const float4 v0 = *(const float4*)(s + (size_t)i * 8);
        const float4 v1 = *(const float4*)(s + (size_t)i * 8 + 4);
        s8v o;
        o[0] = f2b(v0.x); o[1] = f2b(v0.y); o[2] = f2b(v0.z); o[3] = f2b(v0.w);
        o[4] = f2b(v1.x); o[5] = f2b(v1.y); o[6] = f2b(v1.z); o[7] = f2b(v1.w);
        const int cp = (c & ~7) | ((c & 7) ^ (row & 7));
        *(s8v*)(d + (size_t)row * EMB + cp * 8) = o;
    }
}

// NT GEMM via global_load_lds (m97 structure): C = A*W^T + bias.
// A, W are bf16 with swizzled 16B chunks (see cvt_swz). LDS rows unpadded
// (128 B); frag reads address slot (kk*4+quad)^(l16&7) -> bank-uniform.
// FUSED3: 3 matrices (QKV); mat 2 writes V transposed per-head [b][h][d][s].
// mat 0 (Q) output is prescaled by 0.125*log2(e) so attention uses exp2.
template<int NT, bool FUSED3>
__global__ __launch_bounds__(256, 3)
void gemm_bb3(const short* __restrict__ A,
              const short* __restrict__ W0, const short* __restrict__ W1, const short* __restrict__ W2,
              const float* __restrict__ B0, const float* __restrict__ B1, const float* __restrict__ B2,
              void* __restrict__ C0, void* __restrict__ C1, void* __restrict__ C2)
{
    constexpr int JN = NT / 32;
    const int K = EMB, N = EMB;
    const int ntiles = EMB / NT;
    const int mat = blockIdx.x / ntiles;
    const int n0  = (blockIdx.x % ntiles) * NT;
    const int m0  = blockIdx.y * 128;
    const short* W  = (mat == 0) ? W0 : (mat == 1 ? W1 : W2);
    const float* Bi = (mat == 0) ? B0 : (mat == 1 ? B1 : B2);
    void*        C  = (mat == 0) ? C0 : (mat == 1 ? C1 : C2);
    const float qscale = (FUSED3 && mat == 0) ? 0.18033688f : 1.0f;  // 1/8*log2e

    __shared__ __align__(16) short As[128 * 64];
    __shared__ __align__(16) short Ws[NT * 64];

    const int tid  = threadIdx.x;
    const int lane = tid & 63;
    const int wave = tid >> 6;
    const int quad = lane >> 4;
    const int l16  = lane & 15;
    const int l8   = l16 & 7;
    const int wm   = wave >> 1;
    const int wn   = wave & 1;

    f4v acc[4][JN] = {};

    const int srow = lane >> 3;    // staging row within 8-row group
    const int scol = (lane & 7) * 8;

    for (int k0 = 0; k0 < K; k0 += 64) {
        // ---- async DMA staging: A rows wave*32.., W rows wave*(NT/4).. ----
        #pragma unroll
        for (int p = 0; p < 4; ++p) {
            const int rbase = wave * 32 + p * 8;
            gl_lds16(A + (size_t)(m0 + rbase + srow) * K + k0 + scol,
                     As + rbase * 64);
        }
        #pragma unroll
        for (int p = 0; p < NT / 32; ++p) {
            const int rbase = wave * (NT / 4) + p * 8;
            gl_lds16(W + (size_t)(n0 + rbase + srow) * K + k0 + scol,
                     Ws + rbase * 64);
        }
        __syncthreads();   // drains the DMA (vmcnt) + barrier

        #pragma unroll
        for (int kk = 0; kk < 2; ++kk) {
            const int slot = ((kk * 4 + quad) ^ l8) * 8;
            s8v af[4], wf[JN];
            #pragma unroll
            for (int i = 0; i < 4; ++i)
                af[i] = *(const s8v*)(As + (wm * 64 + i * 16 + l16) * 64 + slot);
            #pragma unroll
            for (int j = 0; j < JN; ++j)
                wf[j] = *(const s8v*)(Ws + (wn * (NT / 2) + j * 16 + l16) * 64 + slot);
            #pragma unroll
            for (int i = 0; i < 4; ++i)
                #pragma unroll
                for (int j = 0; j < JN; ++j)
                    acc[i][j] = __builtin_amdgcn_mfma_f32_16x16x32_bf16(
                        af[i], wf[j], acc[i][j], 0, 0, 0);
        }
        __syncthreads();   // all waves done reading before next overwrite
    }

    // C/D layout: col = lane&15 (n), row = quad*4+reg (m)   [m89-verified]
    #pragma unroll
    for (int j = 0; j < JN; ++j) {
        const int n = n0 + wn * (NT / 2) + j * 16 + l16;
        const float bv = Bi[n];
        #pragma unroll
        for (int i = 0; i < 4; ++i) {
            const int mb = m0 + wm * 64 + i * 16 + quad * 4;
            if (FUSED3 && mat == 2) {
                const int bb = mb >> 11, s = mb & 2047;
                s4v ov;
                #pragma unroll
                for (int rr = 0; rr < 4; ++rr) ov[rr] = f2b(acc[i][j][rr] + bv);
                *(s4v*)((short*)C + ((size_t)(bb * 1024 + n)) * SEQ + s) = ov;
            } else if (FUSED3) {
                #pragma unroll
                for (int rr = 0; rr < 4; ++rr)
                    ((short*)C)[(size_t)(mb + rr) * N + n] = f2b((acc[i][j][rr] + bv) * qscale);
            } else {
                #pragma unroll
                for (int rr = 0; rr < 4; ++rr)
                    ((float*)C)[(size_t)(mb + rr) * N + n] = acc[i][j][rr] + bv;
            }
        }
    }
}

// MFMA flash attention v5.
// vs v4: (1) Q comes in prescaled by 0.125*log2e -> p = exp2(s), one trans op
// per element instead of mul+mul+exp; (2) softmax denominator computed by an
// extra ones-vector MFMA alongside PV (C col = lane&15 = q matches oacc; all
// rows equal) -> no per-element rounded-p unpack/accumulate, no butterfly;
// (3) Ks/Vs/Pt use unpadded stride-64 rows with the GEMM-proven XOR chunk
// swizzle (physical chunk = logical ^ (row&7)) on both write and read ->
// bank-uniform ds ops (the 72-pad had bank-stride 4 => 7.4M conflict cycles).
// The O store swizzle (lc ^ (row&7)) cancels against the Pt swizzle, so the
// final LDS read is linear and the global store keeps the out-proj layout.
__global__ __launch_bounds__(256, 2)
void attn_mfma4(const short* Q, const short* __restrict__ Kg,
                const short* __restrict__ Vt, short* O)
{
    const int blk = blockIdx.x;     // 512
    const int qb = blk & 15;
    const int h  = (blk >> 4) & 15;
    const int b  = blk >> 8;
    const int q0 = qb * QT;

    const int tid  = threadIdx.x;
    const int lane = tid & 63;
    const int wave = tid >> 6;
    const int quad = lane >> 4;
    const int l16  = lane & 15;
    const int l8   = l16 & 7;

    __shared__ __align__(16) short Ks[2][64 * 64];   // [key][d]   swizzled
    __shared__ __align__(16) short Vs[2][64 * 64];   // [d][key]   swizzled
    __shared__ __align__(16) short Pt[QT * 64];      // [q][key]   swizzled, wave-private

    // Q B-frags for the whole kernel: [mi][kk]  (Q is prescaled)
    s8v qf[2][2];
    #pragma unroll
    for (int mi = 0; mi < 2; ++mi)
        #pragma unroll
        for (int kk = 0; kk < 2; ++kk)
            qf[mi][kk] = *(const s8v*)(Q + (size_t)(b * SEQ + q0 + wave * 32 + mi * 16 + l16) * EMB
                                         + h * DHEAD + kk * 32 + quad * 8);

    f4v oacc[4][2] = {};   // [j: d-block][mi] -> O^T[d][q]
    f4v sacc[2]    = {};   // ones-MFMA row sums (col = q, all rows equal)
    s8v onef;
    #pragma unroll
    for (int i = 0; i < 8; ++i) onef[i] = (short)0x3F80;   // bf16 1.0

    const int c = tid & 7, r = tid >> 3;
    const int swz = (c ^ (r & 7)) * 8;          // staging chunk swizzle
    const size_t kbase = (size_t)(b * SEQ) * EMB + h * DHEAD;
    const size_t vbase = (size_t)((b * NHEAD + h) * DHEAD) * SEQ;

    // prologue: prefetch tile 0
    s8v ka[2], va[2];
    #pragma unroll
    for (int p = 0; p < 2; ++p) {
        ka[p] = *(const s8v*)(Kg + kbase + (size_t)(r + p * 32) * EMB + c * 8);
        va[p] = *(const s8v*)(Vt + vbase + (size_t)(r + p * 32) * SEQ + c * 8);
    }

    for (int t = 0; t < SEQ / KT; ++t) {
        const int buf = t & 1;
        short* KsB = Ks[buf];
        short* VsB = Vs[buf];

        // write current tile from regs, swizzled ((r+p*32)&7 == r&7)
        #pragma unroll
        for (int p = 0; p < 2; ++p) {
            *(s8v*)(KsB + (r + p * 32) * 64 + swz) = ka[p];
            *(s8v*)(VsB + (r + p * 32) * 64 + swz) = va[p];
        }
        // async prefetch of next tile (stays in flight across the barrier)
        if (t + 1 < SEQ / KT) {
            const int kt2 = (t + 1) * KT;
            #pragma unroll
            for (int p = 0; p < 2; ++p) {
                ka[p] = *(const s8v*)(Kg + kbase + (size_t)(kt2 + r + p * 32) * EMB + c * 8);
                va[p] = *(const s8v*)(Vt + vbase + (size_t)(r + p * 32) * SEQ + kt2 + c * 8);
            }
        }
        bar_lds();   // tile visible; prefetch NOT drained

        // ---- S^T[key][q] = K · Q^T (already in log2 domain) ----
        f4v sc[4][2] = {};
        #pragma unroll
        for (int kk = 0; kk < 2; ++kk) {
            const int ko = ((kk * 4 + quad) ^ l8) * 8;
            s8v kf[4];
            #pragma unroll
            for (int j = 0; j < 4; ++j)
                kf[j] = *(const s8v*)(KsB + (j * 16 + l16) * 64 + ko);
            #pragma unroll
            for (int j = 0; j < 4; ++j)
                #pragma unroll
                for (int mi = 0; mi < 2; ++mi)
                    sc[j][mi] = __builtin_amdgcn_mfma_f32_16x16x32_bf16(
                        kf[j], qf[mi][kk], sc[j][mi], 0, 0, 0);
        }

        // ---- p = 2^s, pack to bf16, store swizzled ----
        #pragma unroll
        for (int j = 0; j < 4; ++j)
            #pragma unroll
            for (int mi = 0; mi < 2; ++mi) {
                union { unsigned u[2]; s4v s; } pv;
                pv.u[0] = pk2(exp2_fast(sc[j][mi][0]), exp2_fast(sc[j][mi][1]));
                pv.u[1] = pk2(exp2_fast(sc[j][mi][2]), exp2_fast(sc[j][mi][3]));
                const int pc = ((j * 2 + (quad >> 1)) ^ l8) * 8 + (quad & 1) * 4;
                *(s4v*)(Pt + (wave * 32 + mi * 16 + l16) * 64 + pc) = pv.s;
            }

        // ---- O^T[d][q] += V^T[d][key] · P^T ; row sums via ones-MFMA ----
        #pragma unroll
        for (int kk = 0; kk < 2; ++kk) {
            const int ko = ((kk * 4 + quad) ^ l8) * 8;
            s8v pf[2];
            #pragma unroll
            for (int mi = 0; mi < 2; ++mi) {
                pf[mi] = *(const s8v*)(Pt + (wave * 32 + mi * 16 + l16) * 64 + ko);
                sacc[mi] = __builtin_amdgcn_mfma_f32_16x16x32_bf16(
                    onef, pf[mi], sacc[mi], 0, 0, 0);
            }
            #pragma unroll
            for (int j = 0; j < 4; ++j) {
                const s8v vf = *(const s8v*)(VsB + (j * 16 + l16) * 64 + ko);
                #pragma unroll
                for (int mi = 0; mi < 2; ++mi)
                    oacc[j][mi] = __builtin_amdgcn_mfma_f32_16x16x32_bf16(
                        vf, pf[mi], oacc[j][mi], 0, 0, 0);
            }
        }
    }

    // ---- denominators: every row of sacc holds the full sum for col q ----
    float inv[2];
    #pragma unroll
    for (int mi = 0; mi < 2; ++mi) inv[mi] = 1.0f / sacc[mi][0];

    // ---- O^T C-layout -> LDS [q][d] packed, swizzled (reuse Pt) ----
    #pragma unroll
    for (int j = 0; j < 4; ++j)
        #pragma unroll
        for (int mi = 0; mi < 2; ++mi) {
            union { unsigned u[2]; s4v s; } ov;
            ov.u[0] = pk2(oacc[j][mi][0] * inv[mi], oacc[j][mi][1] * inv[mi]);
            ov.u[1] = pk2(oacc[j][mi][2] * inv[mi], oacc[j][mi][3] * inv[mi]);
            const int pc = ((j * 2 + (quad >> 1)) ^ l8) * 8 + (quad & 1) * 4;
            *(s4v*)(Pt + (wave * 32 + mi * 16 + l16) * 64 + pc) = ov.s;
        }

    // ---- coalesced store: LDS swizzle cancels the output chunk swizzle,
    //      so read Pt linearly and store at the same physical chunk ----
    const int row = tid >> 1;            // wave-private rows [32w, 32w+32)
    const int cb  = (tid & 1) * 4;
    #pragma unroll
    for (int c4 = 0; c4 < 4; ++c4) {
        const int pcc = cb + c4;         // physical chunk 0..7
        const s8v tt = *(const s8v*)(Pt + row * 64 + pcc * 8);
        *(s8v*)(O + (size_t)(b * SEQ + q0 + row) * EMB + h * DHEAD + pcc * 8) = tt;
    }
}

extern "C" void kernel_launch(void* const* d_in, const int* in_sizes, int n_in,
                              void* d_out, int out_size, void* d_ws, size_t ws_size,
                              hipStream_t stream)
{
    const float* x  = (const float*)d_in[0];
    const float* Wq = (const float*)d_in[1];
    const float* bq = (const float*)d_in[2];
    const float* Wk = (const float*)d_in[3];
    const float* bk = (const float*)d_in[4];
    const float* Wv = (const float*)d_in[5];
    const float* bv = (const float*)d_in[6];
    const float* Wo = (const float*)d_in[7];
    const float* bo = (const float*)d_in[8];
    float* out = (float*)d_out;   // fp32 output

    short* xb  = (short*)d_ws;                       // 4096x1024 bf16, swizzled
    short* Wqb = xb  + (size_t)MTOT * EMB;           // swizzled
    short* Wkb = Wqb + (size_t)EMB * EMB;
    short* Wvb = Wkb + (size_t)EMB * EMB;
    short* Wob = Wvb + (size_t)EMB * EMB;
    short* Qw  = Wob + (size_t)EMB * EMB;            // [token][1024] (Q: plain;
                                                     //  then O: swizzled)
    short* Kw  = Qw  + (size_t)MTOT * EMB;           // [token][1024] plain
    short* Vtw = Kw  + (size_t)MTOT * EMB;           // [b][h][d][s] plain

    cvt_swz<<<dim3(512, 5), 256, 0, stream>>>(x, Wq, Wk, Wv, Wo,
                                              xb, Wqb, Wkb, Wvb, Wob);

    gemm_bb3<128, true><<<dim3(24, 32), 256, 0, stream>>>(
        xb, Wqb, Wkb, Wvb, bq, bk, bv, Qw, Kw, Vtw);

    attn_mfma4<<<dim3(BATCH * NHEAD * (SEQ / QT)), 256, 0, stream>>>(Qw, Kw, Vtw, Qw);

    gemm_bb3<64, false><<<dim3(16, 32), 256, 0, stream>>>(
        Qw, Wob, Wob, Wob, bo, bo, bo, out, out, out);
}